// Round 12
// baseline (158.258 us; speedup 1.0000x reference)
//
#include <hip/hip_runtime.h>
#include <math.h>

#define EPSV 1e-5f

typedef __attribute__((ext_vector_type(8))) short short8_t;   // 8 bf16 (4 VGPRs)
typedef __attribute__((ext_vector_type(4))) float f32x4;      // MFMA acc

// ---------------- workspace layout ----------------
// xsp slot : bf16 x-branch (2,8,192,4096) d-major (conv in)
// zbuf slot: bf16 z (8,8192,192) token-major
// xd  slot : bf16 conv output (2,8,192,4096) d-major
// dtBC : (65536,16) fp32; hend/Pbuf/hinit : (8,128,192,4)
// Mgb: bf16 [2*96][192]; Wxtb: bf16 [16][192]; wbi/wbt: bf16 W_in [384][96]
#define N_XSP   12582912
#define N_ZBUF  12582912
#define N_XD    12582912
#define N_DTBC  1048576
#define N_STATE 786432

__device__ __forceinline__ float siluf(float v) {
  return v / (1.f + __expf(-v));
}

__device__ __forceinline__ unsigned short f2bf(float f) {  // RTNE fp32->bf16
  unsigned int u = __float_as_uint(f);
  u += 0x7fffu + ((u >> 16) & 1u);
  return (unsigned short)(u >> 16);
}

__device__ __forceinline__ float bf2f(unsigned short h) {
  return __uint_as_float(((unsigned int)h) << 16);
}

// ---------------- prep: Mg(bf16) + bf16 W_in + bf16 x_proj ----------------
__global__ __launch_bounds__(256) void k_prep(const float* __restrict__ Wout,
                                              const float* __restrict__ Wf,
                                              const float* __restrict__ Wii,
                                              const float* __restrict__ Wit,
                                              const float* __restrict__ xpw,
                                              unsigned short* __restrict__ Mgb,
                                              unsigned short* __restrict__ wbi,
                                              unsigned short* __restrict__ wbt,
                                              unsigned short* __restrict__ Wxtb) {
  int e = blockIdx.x * 256 + threadIdx.x;
  if (e < 36864) {                     // Mg[k][o] = sum_j Wf[o][half*96+j]*Wout[j][k%192]
    int k = e / 96, o = e - k * 96;
    int half = (k >= 192) ? 1 : 0;
    int c = k - half * 192;
    const float* wfr = Wf + o * 192 + half * 96;
    float acc = 0.f;
#pragma unroll 4
    for (int j = 0; j < 96; ++j) acc += wfr[j] * Wout[j * 192 + c];
    Mgb[(half * 96 + o) * 192 + c] = f2bf(acc);
  } else if (e < 73728) {
    int i = e - 36864;
    wbi[i] = f2bf(Wii[i]);
  } else if (e < 110592) {
    int i = e - 73728;
    wbt[i] = f2bf(Wit[i]);
  } else if (e < 113664) {             // Wxtb[o][c] bf16, rows 14,15 zero
    int i = e - 110592;
    int o = i / 192;
    Wxtb[i] = (o < 14) ? f2bf(xpw[i]) : (unsigned short)0;
  }
}

// ---------------- in_proj via bf16 MFMA (nt-sequential, 4 blocks/CU) ----------------
__global__ __launch_bounds__(256, 4) void k_inproj(const float* __restrict__ img,
                                                   const float* __restrict__ text,
                                                   const unsigned short* __restrict__ wbi,
                                                   const unsigned short* __restrict__ wbt,
                                                   unsigned short* __restrict__ xsph,
                                                   unsigned short* __restrict__ zbufh) {
  __shared__ __align__(16) unsigned short Xbf[64 * 104];  // [t][k] pad 104
  int bx = blockIdx.x;
  int tile = bx & 63, b = (bx >> 6) & 7, s = bx >> 9;
  int n0 = tile * 64;
  int tid = threadIdx.x;
  int w = tid >> 6, lane = tid & 63;
  const float* src = s ? text : img;
  const unsigned short* wsel = s ? wbt : wbi;

  for (int idx = tid; idx < 6144; idx += 256) {
    int c = idx >> 6, t = idx & 63;
    Xbf[t * 104 + c] = f2bf(src[((size_t)b * 96 + c) * 4096 + n0 + t]);
  }
  __syncthreads();

  int arow = lane & 15;
  int acol = (lane >> 4) * 8;
  short8_t af[4][3];
#pragma unroll
  for (int mt = 0; mt < 4; ++mt) {
    const unsigned short* ap = &Xbf[(mt * 16 + arow) * 104 + acol];
    af[mt][0] = *(const short8_t*)(ap);
    af[mt][1] = *(const short8_t*)(ap + 32);
    af[mt][2] = *(const short8_t*)(ap + 64);
  }

  const unsigned short* wbase = wsel + ((size_t)(w * 96 + (lane & 15))) * 96 + ((lane >> 4) * 8);
  int rowoff = (lane >> 4) * 4;
  size_t tokb = (size_t)b * 8192 + (size_t)s * 4096 + n0;

  for (int nt = 0; nt < 6; ++nt) {
    short8_t b0 = *(const short8_t*)(wbase + nt * 16 * 96 + 0);
    short8_t b1 = *(const short8_t*)(wbase + nt * 16 * 96 + 32);
    short8_t b2 = *(const short8_t*)(wbase + nt * 16 * 96 + 64);
    f32x4 acc[4];
    f32x4 zz = {0.f, 0.f, 0.f, 0.f};
#pragma unroll
    for (int mt = 0; mt < 4; ++mt) acc[mt] = zz;
#pragma unroll
    for (int mt = 0; mt < 4; ++mt) {
      acc[mt] = __builtin_amdgcn_mfma_f32_16x16x32_bf16(af[mt][0], b0, acc[mt], 0, 0, 0);
      acc[mt] = __builtin_amdgcn_mfma_f32_16x16x32_bf16(af[mt][1], b1, acc[mt], 0, 0, 0);
      acc[mt] = __builtin_amdgcn_mfma_f32_16x16x32_bf16(af[mt][2], b2, acc[mt], 0, 0, 0);
    }
    if (w < 2) {   // x half -> d-major bf16
      int d = w * 96 + nt * 16 + (lane & 15);
      unsigned short* xp = xsph + (((size_t)s * 8 + b) * 192 + d) * 4096 + n0 + rowoff;
#pragma unroll
      for (int mt = 0; mt < 4; ++mt) {
        f32x4 a = acc[mt];
        uint2 pk;
        pk.x = (unsigned int)f2bf(a[0]) | ((unsigned int)f2bf(a[1]) << 16);
        pk.y = (unsigned int)f2bf(a[2]) | ((unsigned int)f2bf(a[3]) << 16);
        *(uint2*)&xp[mt * 16] = pk;
      }
    } else {       // z half -> token-major bf16
      int ch = (w - 2) * 96 + nt * 16 + (lane & 15);
#pragma unroll
      for (int mt = 0; mt < 4; ++mt) {
        f32x4 a = acc[mt];
        unsigned short* zp = zbufh + (tokb + mt * 16 + rowoff) * 192 + ch;
        zp[0] = f2bf(a[0]); zp[192] = f2bf(a[1]); zp[384] = f2bf(a[2]); zp[576] = f2bf(a[3]);
      }
    }
  }
}

// ---------------- depthwise 3x3 conv + BN + SiLU: bf16 in/out ----------------
__global__ __launch_bounds__(256) void k_conv(
    const unsigned short* __restrict__ xsph,
    const float* __restrict__ cwi, const float* __restrict__ cbi,
    const float* __restrict__ bgi, const float* __restrict__ bbi,
    const float* __restrict__ bmi, const float* __restrict__ bvi,
    const float* __restrict__ cwt, const float* __restrict__ cbt,
    const float* __restrict__ bgt, const float* __restrict__ bbt,
    const float* __restrict__ bmt, const float* __restrict__ bvt,
    unsigned short* __restrict__ xdh) {
  int bid = blockIdx.x;
  int img = bid / 96;                 // 0..15
  int d0 = (bid - img * 96) * 2;
  int widx = threadIdx.x >> 6;
  int lane = threadIdx.x & 63;
  int d = d0 + (widx >> 1);
  int half = widx & 1;
  int s = img >> 3;
  const float* cw = s ? cwt : cwi;
  const float* cb = s ? cbt : cbi;
  const float* bg = s ? bgt : bgi;
  const float* bb2 = s ? bbt : bbi;
  const float* bm = s ? bmt : bmi;
  const float* bv = s ? bvt : bvi;
  const unsigned short* src = xsph + ((size_t)img * 192 + d) * 4096;
  unsigned short* dst = xdh + ((size_t)img * 192 + d) * 4096;
  float c0 = cw[d * 9 + 0], c1 = cw[d * 9 + 1], c2 = cw[d * 9 + 2];
  float c3 = cw[d * 9 + 3], c4 = cw[d * 9 + 4], c5 = cw[d * 9 + 5];
  float c6 = cw[d * 9 + 6], c7 = cw[d * 9 + 7], c8 = cw[d * 9 + 8];
  float sc = bg[d] * rsqrtf(bv[d] + EPSV);
  float eb = (cb[d] - bm[d]) * sc + bb2[d];
  int h0 = half * 32;
  float pc = (h0 > 0) ? bf2f(src[(h0 - 1) * 64 + lane]) : 0.f;
  float cc = bf2f(src[h0 * 64 + lane]);
  float nc = bf2f(src[(h0 + 1) * 64 + lane]);
  float t;
  t = __shfl_up(pc, 1);  float pl = (lane == 0) ? 0.f : t;
  t = __shfl_down(pc, 1); float pr = (lane == 63) ? 0.f : t;
  t = __shfl_up(cc, 1);  float cl = (lane == 0) ? 0.f : t;
  t = __shfl_down(cc, 1); float cr = (lane == 63) ? 0.f : t;
#pragma unroll 4
  for (int i = 0; i < 32; ++i) {
    int h = h0 + i;
    float fut = (h + 2 <= 63) ? bf2f(src[(h + 2) * 64 + lane]) : 0.f;
    t = __shfl_up(nc, 1);  float nl = (lane == 0) ? 0.f : t;
    t = __shfl_down(nc, 1); float nr = (lane == 63) ? 0.f : t;
    float a = pl * c0 + pc * c1 + pr * c2
            + cl * c3 + cc * c4 + cr * c5
            + nl * c6 + nc * c7 + nr * c8;
    a = a * sc + eb;
    dst[h * 64 + lane] = f2bf(a / (1.f + __expf(-a)));
    pl = cl; pc = cc; pr = cr;
    cl = nl; cc = nc; cr = nr;
    nc = fut;
  }
}

// ---------------- scan pass A: staged-MFMA x_proj + chunk scan (low LDS) ----------------
__global__ __launch_bounds__(192) void k_scanA(const unsigned short* __restrict__ xdh,
                                               const unsigned short* __restrict__ Wxtb,
                                               const float* __restrict__ dtw,
                                               const float* __restrict__ dtbias,
                                               const float* __restrict__ Alog,
                                               float* __restrict__ dtBC,
                                               float* __restrict__ hend,
                                               float* __restrict__ Pbuf) {
  __shared__ __align__(16) unsigned short Xt16[16 * 200];
  __shared__ __align__(16) float SBC[64 * 16];
  int c = blockIdx.x & 127, b = blockIdx.x >> 7;
  int s = c >> 6, cl = c & 63;
  int d = threadIdx.x;
  int w = d >> 6, lane = d & 63;
  int tokbase = b * 8192 + c * 64;

  const unsigned short* xrow = xdh + (((size_t)s * 8 + b) * 192 + d) * 4096 + cl * 64;
  short8_t xr8[8];
#pragma unroll
  for (int i = 0; i < 8; ++i) xr8[i] = *(const short8_t*)(xrow + i * 8);

  const unsigned short* wb = Wxtb + (size_t)(lane & 15) * 192 + ((lane >> 4) * 8);
  short8_t bfx[6];
#pragma unroll
  for (int ks = 0; ks < 6; ++ks) bfx[ks] = *(const short8_t*)(wb + ks * 32);

  float w0 = dtw[d * 6 + 0], w1 = dtw[d * 6 + 1], w2 = dtw[d * 6 + 2];
  float w3 = dtw[d * 6 + 3], w4 = dtw[d * 6 + 4], w5 = dtw[d * 6 + 5];
  float bb = dtbias[d];
  float4 al = *(const float4*)&Alog[d * 4];
  float A0 = -__expf(al.x), A1 = -__expf(al.y), A2 = -__expf(al.z), A3 = -__expf(al.w);

  int arow = lane & 15, acol = (lane >> 4) * 8;
#pragma unroll
  for (int r = 0; r < 4; ++r) {
    __syncthreads();
#pragma unroll
    for (int tt = 0; tt < 16; ++tt) {
      int i = (r * 16 + tt) >> 3, j = tt & 7;
      Xt16[tt * 200 + d] = (unsigned short)xr8[i][j];
    }
    __syncthreads();
    if (w == (r % 3)) {
      f32x4 a4 = {0.f, 0.f, 0.f, 0.f};
#pragma unroll
      for (int ks = 0; ks < 6; ++ks) {
        short8_t a = *(const short8_t*)&Xt16[arow * 200 + acol + ks * 32];
        a4 = __builtin_amdgcn_mfma_f32_16x16x32_bf16(a, bfx[ks], a4, 0, 0, 0);
      }
      int tt0 = r * 16 + (lane >> 4) * 4, o = lane & 15;
#pragma unroll
      for (int rr = 0; rr < 4; ++rr) {
        SBC[(tt0 + rr) * 16 + o] = a4[rr];
        dtBC[(size_t)(tokbase + tt0 + rr) * 16 + o] = a4[rr];
      }
    }
  }
  __syncthreads();

  bool fastp = fabsf(A0 + 1.f) < 1e-4f && fabsf(A1 + 2.f) < 2e-4f &&
               fabsf(A2 + 3.f) < 3e-4f && fabsf(A3 + 4.f) < 4e-4f;
  float h0 = 0.f, h1 = 0.f, h2 = 0.f, h3 = 0.f, sd = 0.f;
  if (fastp) {
#pragma unroll
    for (int i = 0; i < 8; ++i)
#pragma unroll
      for (int j = 0; j < 8; ++j) {
        int l2 = i * 8 + j;
        float4 s0 = *(const float4*)&SBC[l2 * 16 + 0];
        float4 s1 = *(const float4*)&SBC[l2 * 16 + 4];
        float4 s2 = *(const float4*)&SBC[l2 * 16 + 8];
        float pre = bb + w0 * s0.x + w1 * s0.y + w2 * s0.z + w3 * s0.w + w4 * s1.x + w5 * s1.y;
        float ex = __expf(pre);
        float opx = 1.f + ex;
        float e1 = __builtin_amdgcn_rcpf(opx);
        float delta = (pre > 15.f) ? pre : __logf(opx);
        sd += delta;
        float e2 = e1 * e1, e3 = e2 * e1, e4 = e2 * e2;
        float dx = delta * bf2f((unsigned short)xr8[i][j]);
        h0 = e1 * h0 + dx * s1.z;
        h1 = e2 * h1 + dx * s1.w;
        h2 = e3 * h2 + dx * s2.x;
        h3 = e4 * h3 + dx * s2.y;
      }
  } else {
#pragma unroll
    for (int i = 0; i < 8; ++i)
#pragma unroll
      for (int j = 0; j < 8; ++j) {
        int l2 = i * 8 + j;
        float4 s0 = *(const float4*)&SBC[l2 * 16 + 0];
        float4 s1 = *(const float4*)&SBC[l2 * 16 + 4];
        float4 s2 = *(const float4*)&SBC[l2 * 16 + 8];
        float pre = bb + w0 * s0.x + w1 * s0.y + w2 * s0.z + w3 * s0.w + w4 * s1.x + w5 * s1.y;
        float ex = __expf(pre);
        float delta = (pre > 15.f) ? pre : __logf(1.f + ex);
        sd += delta;
        float dx = delta * bf2f((unsigned short)xr8[i][j]);
        h0 = __expf(delta * A0) * h0 + dx * s1.z;
        h1 = __expf(delta * A1) * h1 + dx * s1.w;
        h2 = __expf(delta * A2) * h2 + dx * s2.x;
        h3 = __expf(delta * A3) * h3 + dx * s2.y;
      }
  }
  size_t o = (((size_t)b * 128 + c) * 192 + d) * 4;
  *(float4*)&hend[o] = make_float4(h0, h1, h2, h3);
  if (fastp) {
    float p1 = __expf(-sd);
    float p2 = p1 * p1;
    *(float4*)&Pbuf[o] = make_float4(p1, p2, p2 * p1, p2 * p2);
  } else {
    *(float4*)&Pbuf[o] = make_float4(__expf(A0 * sd), __expf(A1 * sd), __expf(A2 * sd), __expf(A3 * sd));
  }
}

// ---------------- scan pass 2: cross-chunk combine (128 chunks) ----------------
__global__ __launch_bounds__(256) void k_scan2(const float* __restrict__ hend,
                                               const float* __restrict__ Pbuf,
                                               float* __restrict__ hinit) {
  int e = blockIdx.x * 256 + threadIdx.x;
  if (e >= 8 * 768) return;
  int b = e / 768, r = e - b * 768;
  float h = 0.f;
#pragma unroll 4
  for (int c = 0; c < 128; ++c) {
    int a = (b * 128 + c) * 768 + r;
    hinit[a] = h;
    h = Pbuf[a] * h + hend[a];
  }
}

// ---------------- merged: scan replay -> LDS y -> LayerNorm+gate -> out-proj GEMM ----------------
// 512 blocks x 384 thr. Group g (192 thr) replays chunk c = g*64 + tile into Xbf[g];
// then 6 waves do LN+gate in place; then bf16 MFMA GEMM (K=384 over both kc) -> C store.
__global__ __launch_bounds__(384, 3) void k_scanout(
    const unsigned short* __restrict__ xdh,
    const float* __restrict__ dtBC,
    const float* __restrict__ dtw,
    const float* __restrict__ dtbias,
    const float* __restrict__ Alog,
    const float* __restrict__ Dskip,
    const float* __restrict__ hinit,
    const unsigned short* __restrict__ zbufh,
    const float* __restrict__ lng,
    const float* __restrict__ lnb,
    const unsigned short* __restrict__ Mgb,
    float* __restrict__ out) {
  __shared__ __align__(16) unsigned short Xbf[2][64 * 200];  // y then gated, [t][k]
  __shared__ __align__(16) float SBC2[2][64 * 16];
  int tile = blockIdx.x & 63, b = blockIdx.x >> 6;
  int n0 = tile * 64;
  int tid = threadIdx.x;
  int g = (tid >= 192) ? 1 : 0;
  int d = tid - g * 192;
  int c = g * 64 + tile;           // chunk: s = g, cl = tile
  int tokbase = b * 8192 + c * 64;

  // ---- scan phase (per group) ----
  float w0 = dtw[d * 6 + 0], w1 = dtw[d * 6 + 1], w2 = dtw[d * 6 + 2];
  float w3 = dtw[d * 6 + 3], w4 = dtw[d * 6 + 4], w5 = dtw[d * 6 + 5];
  float bb = dtbias[d];
  float4 al = *(const float4*)&Alog[d * 4];
  float A0 = -__expf(al.x), A1 = -__expf(al.y), A2 = -__expf(al.z), A3 = -__expf(al.w);
  float Dv = Dskip[d];
  float* sbc = &SBC2[g][0];
  for (int idx = d; idx < 1024; idx += 192) sbc[idx] = dtBC[(size_t)tokbase * 16 + idx];
  const unsigned short* xrow = xdh + (((size_t)g * 8 + b) * 192 + d) * 4096 + tile * 64;
  short8_t xr8[8];
#pragma unroll
  for (int i = 0; i < 8; ++i) xr8[i] = *(const short8_t*)(xrow + i * 8);
  size_t o = (((size_t)b * 128 + c) * 192 + d) * 4;
  float4 hv = *(const float4*)&hinit[o];
  float h0 = hv.x, h1 = hv.y, h2 = hv.z, h3 = hv.w;
  bool fastp = fabsf(A0 + 1.f) < 1e-4f && fabsf(A1 + 2.f) < 2e-4f &&
               fabsf(A2 + 3.f) < 3e-4f && fabsf(A3 + 4.f) < 4e-4f;
  __syncthreads();
  unsigned short* ylds = &Xbf[g][d];
  if (fastp) {
#pragma unroll
    for (int i = 0; i < 8; ++i)
#pragma unroll
      for (int j = 0; j < 8; ++j) {
        int l2 = i * 8 + j;
        float4 s0 = *(const float4*)&sbc[l2 * 16 + 0];
        float4 s1 = *(const float4*)&sbc[l2 * 16 + 4];
        float4 s2 = *(const float4*)&sbc[l2 * 16 + 8];
        float4 s3 = *(const float4*)&sbc[l2 * 16 + 12];
        float pre = bb + w0 * s0.x + w1 * s0.y + w2 * s0.z + w3 * s0.w + w4 * s1.x + w5 * s1.y;
        float ex = __expf(pre);
        float opx = 1.f + ex;
        float e1 = __builtin_amdgcn_rcpf(opx);
        float delta = (pre > 15.f) ? pre : __logf(opx);
        float e2 = e1 * e1, e3 = e2 * e1, e4 = e2 * e2;
        float xv = bf2f((unsigned short)xr8[i][j]);
        float dx = delta * xv;
        h0 = e1 * h0 + dx * s1.z;
        h1 = e2 * h1 + dx * s1.w;
        h2 = e3 * h2 + dx * s2.x;
        h3 = e4 * h3 + dx * s2.y;
        ylds[l2 * 200] = f2bf(h0 * s2.z + h1 * s2.w + h2 * s3.x + h3 * s3.y + Dv * xv);
      }
  } else {
#pragma unroll
    for (int i = 0; i < 8; ++i)
#pragma unroll
      for (int j = 0; j < 8; ++j) {
        int l2 = i * 8 + j;
        float4 s0 = *(const float4*)&sbc[l2 * 16 + 0];
        float4 s1 = *(const float4*)&sbc[l2 * 16 + 4];
        float4 s2 = *(const float4*)&sbc[l2 * 16 + 8];
        float4 s3 = *(const float4*)&sbc[l2 * 16 + 12];
        float pre = bb + w0 * s0.x + w1 * s0.y + w2 * s0.z + w3 * s0.w + w4 * s1.x + w5 * s1.y;
        float ex = __expf(pre);
        float delta = (pre > 15.f) ? pre : __logf(1.f + ex);
        float xv = bf2f((unsigned short)xr8[i][j]);
        float dx = delta * xv;
        h0 = __expf(delta * A0) * h0 + dx * s1.z;
        h1 = __expf(delta * A1) * h1 + dx * s1.w;
        h2 = __expf(delta * A2) * h2 + dx * s2.x;
        h3 = __expf(delta * A3) * h3 + dx * s2.y;
        ylds[l2 * 200] = f2bf(h0 * s2.z + h1 * s2.w + h2 * s3.x + h3 * s3.y + Dv * xv);
      }
  }
  __syncthreads();

  // ---- LN + gate phase: 6 waves over 128 tokens, in place ----
  int w = tid >> 6, lane = tid & 63;
  float lg0 = lng[lane], lg1 = lng[lane + 64], lg2 = lng[lane + 128];
  float lb0 = lnb[lane], lb1 = lnb[lane + 64], lb2 = lnb[lane + 128];
  for (int t = w; t < 128; t += 6) {
    int kc = t >> 6, tl = t & 63;
    size_t tok = (size_t)b * 8192 + (size_t)kc * 4096 + n0 + tl;
    unsigned short* yr = &Xbf[kc][tl * 200];
    const unsigned short* zr = zbufh + tok * 192;
    float y0 = bf2f(yr[lane]), y1 = bf2f(yr[lane + 64]), y2 = bf2f(yr[lane + 128]);
    float z0 = bf2f(zr[lane]), z1 = bf2f(zr[lane + 64]), z2 = bf2f(zr[lane + 128]);
    float sm = y0 + y1 + y2;
    float sq = y0 * y0 + y1 * y1 + y2 * y2;
#pragma unroll
    for (int off = 32; off; off >>= 1) {
      sm += __shfl_xor(sm, off);
      sq += __shfl_xor(sq, off);
    }
    float mu = sm * (1.f / 192.f);
    float var = sq * (1.f / 192.f) - mu * mu;
    float rstd = rsqrtf(var + EPSV);
    yr[lane]       = f2bf(((y0 - mu) * rstd * lg0 + lb0) * siluf(z0));
    yr[lane + 64]  = f2bf(((y1 - mu) * rstd * lg1 + lb1) * siluf(z1));
    yr[lane + 128] = f2bf(((y2 - mu) * rstd * lg2 + lb2) * siluf(z2));
  }
  __syncthreads();

  // ---- GEMM phase: 6 waves x 16 outs, K=192 x 2 kc ----
  const unsigned short* bb_p = Mgb + ((size_t)(w * 16 + (lane & 15))) * 192 + ((lane >> 4) * 8);
  short8_t bfr[2][6];
#pragma unroll
  for (int kc = 0; kc < 2; ++kc)
#pragma unroll
    for (int ks = 0; ks < 6; ++ks)
      bfr[kc][ks] = *(const short8_t*)(bb_p + kc * 96 * 192 + ks * 32);

  f32x4 acc[4];
  f32x4 zz = {0.f, 0.f, 0.f, 0.f};
#pragma unroll
  for (int mt = 0; mt < 4; ++mt) acc[mt] = zz;
  int arow = lane & 15, acol = (lane >> 4) * 8;
#pragma unroll
  for (int kc = 0; kc < 2; ++kc) {
#pragma unroll
    for (int mt = 0; mt < 4; ++mt) {
      const unsigned short* ap = &Xbf[kc][(mt * 16 + arow) * 200 + acol];
#pragma unroll
      for (int ks = 0; ks < 6; ++ks) {
        short8_t a = *(const short8_t*)(ap + ks * 32);
        acc[mt] = __builtin_amdgcn_mfma_f32_16x16x32_bf16(a, bfr[kc][ks], acc[mt], 0, 0, 0);
      }
    }
  }
  int rowoff = (lane >> 4) * 4;
  float* op = out + ((size_t)b * 96 + w * 16 + (lane & 15)) * 4096 + n0 + rowoff;
#pragma unroll
  for (int mt = 0; mt < 4; ++mt) {
    f32x4 a = acc[mt];
    *(float4*)&op[mt * 16] = make_float4(a[0], a[1], a[2], a[3]);
  }
}

extern "C" void kernel_launch(void* const* d_in, const int* in_sizes, int n_in,
                              void* d_out, int out_size, void* d_ws, size_t ws_size,
                              hipStream_t stream) {
  (void)in_sizes; (void)n_in; (void)out_size; (void)ws_size;
  const float* img  = (const float*)d_in[0];
  const float* text = (const float*)d_in[1];
  const float* Wii  = (const float*)d_in[2];
  const float* Wit  = (const float*)d_in[3];
  const float* cwi  = (const float*)d_in[4];
  const float* cbi  = (const float*)d_in[5];
  const float* bgi  = (const float*)d_in[6];
  const float* bbi  = (const float*)d_in[7];
  const float* bmi  = (const float*)d_in[8];
  const float* bvi  = (const float*)d_in[9];
  const float* cwt  = (const float*)d_in[10];
  const float* cbt  = (const float*)d_in[11];
  const float* bgt  = (const float*)d_in[12];
  const float* bbt  = (const float*)d_in[13];
  const float* bmt  = (const float*)d_in[14];
  const float* bvt  = (const float*)d_in[15];
  const float* xpw  = (const float*)d_in[16];
  const float* dtw  = (const float*)d_in[17];
  const float* dtb  = (const float*)d_in[18];
  const float* Alog = (const float*)d_in[19];
  const float* Dsk  = (const float*)d_in[20];
  const float* lng  = (const float*)d_in[21];
  const float* lnb  = (const float*)d_in[22];
  const float* Wout = (const float*)d_in[23];
  const float* Wfus = (const float*)d_in[24];

  float* ws    = (float*)d_ws;
  unsigned short* xsph  = (unsigned short*)ws;
  unsigned short* zbufh = (unsigned short*)(ws + N_XSP);
  unsigned short* xdh   = (unsigned short*)(ws + N_XSP + N_ZBUF);
  float* dtBC  = ws + N_XSP + N_ZBUF + N_XD;
  float* hend  = dtBC + N_DTBC;
  float* Pbuf  = hend + N_STATE;
  float* hinit = Pbuf + N_STATE;
  unsigned short* Mgb  = (unsigned short*)(hinit + N_STATE);
  unsigned short* Wxtb = Mgb + 36864;
  unsigned short* wbi  = Wxtb + 3072;
  unsigned short* wbt  = wbi + 36864;
  float* out   = (float*)d_out;

  hipLaunchKernelGGL(k_prep, dim3(444), dim3(256), 0, stream, Wout, Wfus, Wii, Wit, xpw, Mgb, wbi, wbt, Wxtb);
  hipLaunchKernelGGL(k_inproj, dim3(1024), dim3(256), 0, stream, img, text, wbi, wbt, xsph, zbufh);
  hipLaunchKernelGGL(k_conv, dim3(1536), dim3(256), 0, stream, xsph,
                     cwi, cbi, bgi, bbi, bmi, bvi, cwt, cbt, bgt, bbt, bmt, bvt, xdh);
  hipLaunchKernelGGL(k_scanA, dim3(1024), dim3(192), 0, stream, xdh, Wxtb, dtw, dtb, Alog, dtBC, hend, Pbuf);
  hipLaunchKernelGGL(k_scan2, dim3(24), dim3(256), 0, stream, hend, Pbuf, hinit);
  hipLaunchKernelGGL(k_scanout, dim3(512), dim3(384), 0, stream, xdh, dtBC, dtw, dtb, Alog, Dsk,
                     hinit, zbufh, lng, lnb, Mgb, out);
}